// Round 3
// baseline (360.964 us; speedup 1.0000x reference)
//
#include <hip/hip_runtime.h>
#include <math.h>

// ChannelDropout: out[b,c,t] = sig[b,c,t] * kept[b,c] / (1e-8 + proba[b,c])
//   kept[b,c]  = ||pos[b,c] - center|| > 0.2
//   proba[b,c] = mean_i( ||pos[b,c] - mc[i]|| > 0.2 ), i in [0,100)
//
// Fused, wave-per-row version (round-2 split regressed: dispatch-boundary
// overhead > prologue savings; reverted to fused).
//  - 256-thread block = 4 waves = 4 rows; grid = ceil(rows/4) = 4368.
//  - Each wave computes its row's scale ONCE (lane-parallel MC count +
//    6-step __shfl_xor butterfly) -> 4x less redundant prologue work than
//    the wave-redundant-per-block round-1 version.
//  - Batch-0 of the stream (6 float4 per lane, 24 VGPRs) is staged BEFORE
//    the scale chain so HBM load latency overlaps it (round-1's win).
//  - No LDS, no __syncthreads, nontemporal loads/stores (touch-once
//    streams, 419 MB >> L3).
//  - NOTE numerics: keep sqrtf(d2) > 0.2f (not d2 > 0.04f) so borderline
//    comparisons round identically to the JAX reference.

typedef float v4f __attribute__((ext_vector_type(4)));

__global__ __launch_bounds__(256) void channel_dropout_kernel(
    const float* __restrict__ sig,
    const float* __restrict__ pos,
    const float* __restrict__ center,
    const float* __restrict__ mc,
    float* __restrict__ out,
    int rows, int T, int NMC)
{
    const int t    = threadIdx.x;
    const int wid  = t >> 6;               // wave id 0..3
    const int lane = t & 63;

    const int row = blockIdx.x * 4 + wid;  // one row per wave
    if (row >= rows) return;

    const size_t base = (size_t)row * (size_t)T;
    const int n4 = T >> 2;                 // 750 for T=3000
    const v4f* __restrict__ in4  = (const v4f*)(sig + base);
    v4f* __restrict__       out4 = (v4f*)(out + base);

    // ---- stage batch 0 (6 float4 per lane, covers n4 <= 384) -------------
    v4f v[6];
    #pragma unroll
    for (int u = 0; u < 6; ++u) {
        const int i = lane + u * 64;
        if (i < n4) v[u] = __builtin_nontemporal_load(in4 + i);
    }

    // ---- per-wave scale (overlaps the in-flight batch-0 loads) -----------
    const float px = pos[2 * (size_t)row + 0];
    const float py = pos[2 * (size_t)row + 1];
    float cnt = 0.0f;
    for (int i = lane; i < NMC; i += 64) { // lanes 0-35: 2 iters, rest: 1
        const float dx = px - mc[2 * i + 0];
        const float dy = py - mc[2 * i + 1];
        cnt += (sqrtf(dx * dx + dy * dy) > 0.2f) ? 1.0f : 0.0f;
    }
    #pragma unroll
    for (int off = 32; off > 0; off >>= 1)  // butterfly: all lanes get sum
        cnt += __shfl_xor(cnt, off, 64);

    const float ddx  = px - center[0];
    const float ddy  = py - center[1];
    const float kept = (sqrtf(ddx * ddx + ddy * ddy) > 0.2f) ? 1.0f : 0.0f;
    const float scale = kept / (1e-8f + cnt / (float)NMC);

    // ---- store batch 0 ----------------------------------------------------
    #pragma unroll
    for (int u = 0; u < 6; ++u) {
        const int i = lane + u * 64;
        if (i < n4) {
            v4f r = v[u];
            r *= scale;
            __builtin_nontemporal_store(r, out4 + i);
        }
    }

    // ---- remaining batches (scale known; latency hidden by TLP) ----------
    for (int i0 = 384; i0 < n4; i0 += 384) {
        v4f w[6];
        #pragma unroll
        for (int u = 0; u < 6; ++u) {
            const int i = i0 + lane + u * 64;
            if (i < n4) w[u] = __builtin_nontemporal_load(in4 + i);
        }
        #pragma unroll
        for (int u = 0; u < 6; ++u) {
            const int i = i0 + lane + u * 64;
            if (i < n4) {
                v4f r = w[u];
                r *= scale;
                __builtin_nontemporal_store(r, out4 + i);
            }
        }
    }

    // scalar tail for T % 4 != 0 (not hit for T=3000)
    for (int i = (n4 << 2) + lane; i < T; i += 64) {
        out[base + i] = sig[base + i] * scale;
    }
}

extern "C" void kernel_launch(void* const* d_in, const int* in_sizes, int n_in,
                              void* d_out, int out_size, void* d_ws, size_t ws_size,
                              hipStream_t stream) {
    const float* sig    = (const float*)d_in[0];  // (B, C, T) f32
    const float* pos    = (const float*)d_in[1];  // (B, C, 2) f32
    const float* center = (const float*)d_in[2];  // (2,)      f32
    const float* mc     = (const float*)d_in[3];  // (N, 2)    f32
    float* out          = (float*)d_out;          // (B, C, T) f32

    const int rows = in_sizes[1] / 2;             // B*C = 17472
    const int T    = in_sizes[0] / rows;          // 3000
    const int NMC  = in_sizes[3] / 2;             // 100

    const int blocks = (rows + 3) / 4;            // 4 rows (waves) per block
    channel_dropout_kernel<<<blocks, 256, 0, stream>>>(
        sig, pos, center, mc, out, rows, T, NMC);
}

// Round 4
// 337.143 us; speedup vs baseline: 1.0707x; 1.0707x over previous
//
#include <hip/hip_runtime.h>
#include <math.h>

// ChannelDropout: out[b,c,t] = sig[b,c,t] * kept[b,c] / (1e-8 + proba[b,c])
//   kept[b,c]  = ||pos[b,c] - center|| > 0.2
//   proba[b,c] = mean_i( ||pos[b,c] - mc[i]|| > 0.2 ), i in [0,100)
//
// Round-1 structure (best measured: block-per-row, 4-deep float4 staging,
// wave-redundant scale, no LDS/no barrier, nontemporal) + kept-skip:
//  - kept depends only on pos/center (cheap). If kept==0 the output row is
//    exactly 0.0 regardless of sig -> store zeros, SKIP the 12 KB sig read
//    and the 100-center MC loop. ~12% of rows -> ~25 MB less read traffic.
//  - Round-3 lesson: keep staging at 4-deep; 6-deep (48 live VGPRs + state)
//    crossed the 64-VGPR occupancy cliff and regressed 10%.
//  - Round-2 lesson: keep it fused; a split pays a dispatch boundary.
//  - NOTE numerics: keep sqrtf(d2) > 0.2f (not d2 > 0.04f) so borderline
//    comparisons round identically to the JAX reference.

typedef float v4f __attribute__((ext_vector_type(4)));

__global__ __launch_bounds__(256) void channel_dropout_kernel(
    const float* __restrict__ sig,
    const float* __restrict__ pos,
    const float* __restrict__ center,
    const float* __restrict__ mc,
    float* __restrict__ out,
    int T, int NMC)
{
    const int row  = blockIdx.x;           // b*C + c
    const int t    = threadIdx.x;
    const int lane = t & 63;

    const size_t base = (size_t)row * (size_t)T;
    const int n4 = T >> 2;                 // 750 float4 per row (T=3000)
    const v4f* __restrict__ in4  = (const v4f*)(sig + base);
    v4f* __restrict__       out4 = (v4f*)(out + base);

    // ---- kept check first (pos/center are L2-hot; block-uniform) ---------
    const float px  = pos[2 * (size_t)row + 0];
    const float py  = pos[2 * (size_t)row + 1];
    const float ddx = px - center[0];
    const float ddy = py - center[1];
    const bool kept = sqrtf(ddx * ddx + ddy * ddy) > 0.2f;

    if (!kept) {
        // dropped channel: out row is exactly 0 — no sig read, no MC loop
        const v4f z = {0.0f, 0.0f, 0.0f, 0.0f};
        #pragma unroll
        for (int u = 0; u < 4; ++u) {
            const int i = t + u * 256;
            if (i < n4) __builtin_nontemporal_store(z, out4 + i);
        }
        for (int i = t + 1024; i < n4; i += 256)
            __builtin_nontemporal_store(z, out4 + i);
        for (int i = (n4 << 2) + t; i < T; i += 256)
            out[base + i] = 0.0f;
        return;
    }

    // ---- stage the streaming loads before the MC scale chain -------------
    v4f v[4];
    #pragma unroll
    for (int u = 0; u < 4; ++u) {
        const int i = t + u * 256;
        if (i < n4) v[u] = __builtin_nontemporal_load(in4 + i);
    }

    // ---- per-wave redundant MC count (no barrier, no LDS) ----------------
    float cnt = 0.0f;
    for (int i = lane; i < NMC; i += 64) { // lanes 0-35: 2 iters, rest: 1
        const float dx = px - mc[2 * i + 0];
        const float dy = py - mc[2 * i + 1];
        cnt += (sqrtf(dx * dx + dy * dy) > 0.2f) ? 1.0f : 0.0f;
    }
    #pragma unroll
    for (int off = 32; off > 0; off >>= 1)  // butterfly: all lanes get sum
        cnt += __shfl_xor(cnt, off, 64);

    const float scale = 1.0f / (1e-8f + cnt / (float)NMC);  // kept == 1

    // ---- scale + store ----------------------------------------------------
    #pragma unroll
    for (int u = 0; u < 4; ++u) {
        const int i = t + u * 256;
        if (i < n4) {
            v4f r = v[u];
            r *= scale;
            __builtin_nontemporal_store(r, out4 + i);
        }
    }
    // generic remainder for n4 > 1024 (not hit at T=3000, kept for safety)
    for (int i = t + 1024; i < n4; i += 256) {
        v4f r = __builtin_nontemporal_load(in4 + i);
        r *= scale;
        __builtin_nontemporal_store(r, out4 + i);
    }
    // scalar tail for T % 4 != 0 (not hit for T=3000)
    for (int i = (n4 << 2) + t; i < T; i += 256) {
        out[base + i] = sig[base + i] * scale;
    }
}

extern "C" void kernel_launch(void* const* d_in, const int* in_sizes, int n_in,
                              void* d_out, int out_size, void* d_ws, size_t ws_size,
                              hipStream_t stream) {
    const float* sig    = (const float*)d_in[0];  // (B, C, T) f32
    const float* pos    = (const float*)d_in[1];  // (B, C, 2) f32
    const float* center = (const float*)d_in[2];  // (2,)      f32
    const float* mc     = (const float*)d_in[3];  // (N, 2)    f32
    float* out          = (float*)d_out;          // (B, C, T) f32

    const int rows = in_sizes[1] / 2;             // B*C = 17472
    const int T    = in_sizes[0] / rows;          // 3000
    const int NMC  = in_sizes[3] / 2;             // 100

    channel_dropout_kernel<<<rows, 256, 0, stream>>>(
        sig, pos, center, mc, out, T, NMC);
}